// Round 9
// baseline (4663.346 us; speedup 1.0000x reference)
//
#include <hip/hip_runtime.h>

#define TT 512
#define BB 64
#define II 1024
#define HH 1024
#define GG 4096   /* 4*H */
#define BH 65536  /* B*H */
#define NBLK 128

typedef __attribute__((ext_vector_type(8))) short bf16x8;
typedef __attribute__((ext_vector_type(4))) float f32x4;
typedef __attribute__((ext_vector_type(4))) unsigned u32x4;

__device__ __forceinline__ float bf2f(unsigned short u) {
  union { unsigned int i; float f; } v; v.i = ((unsigned int)u) << 16; return v.f;
}
__device__ __forceinline__ unsigned short f2bf(float f) {
  union { float f; unsigned int i; } v; v.f = f;
  return (unsigned short)((v.i + 0x7FFFu + ((v.i >> 16) & 1u)) >> 16);
}
__device__ __forceinline__ bf16x8 pack8(float4 a, float4 b) {
  union { bf16x8 v; unsigned short u[8]; } p;
  p.u[0] = f2bf(a.x); p.u[1] = f2bf(a.y); p.u[2] = f2bf(a.z); p.u[3] = f2bf(a.w);
  p.u[4] = f2bf(b.x); p.u[5] = f2bf(b.y); p.u[6] = f2bf(b.z); p.u[7] = f2bf(b.w);
  return p.v;
}
__device__ __forceinline__ float sigmoid_f(float x) { return 1.0f / (1.0f + __expf(-x)); }
__device__ __forceinline__ float tanh_f(float x) {
  float e = __expf(-2.0f * fabsf(x));
  float t = (1.0f - e) / (1.0f + e);
  return copysignf(t, x);
}

__device__ __forceinline__ void st32_uc(unsigned* p, unsigned v) {
  __hip_atomic_store(p, v, __ATOMIC_RELAXED, __HIP_MEMORY_SCOPE_AGENT);
}
__device__ __forceinline__ unsigned ld32_uc(const unsigned* p) {
  return __hip_atomic_load(p, __ATOMIC_RELAXED, __HIP_MEMORY_SCOPE_AGENT);
}
// 16B write-through to the coherence point (non-atomic; aligned 16B = 1 transaction)
__device__ __forceinline__ void st128_uc(void* p, u32x4 v) {
  asm volatile("global_store_dwordx4 %0, %1, off sc0 sc1" :: "v"(p), "v"(v) : "memory");
}

// ---------------- x f32 -> bf16 chunk conversion ----------------
__global__ __launch_bounds__(256) void wdlstm_xconv(
    const float* __restrict__ xc, unsigned short* __restrict__ xbf, int n4) {
  int stride = gridDim.x * blockDim.x;
  for (int i = blockIdx.x * blockDim.x + threadIdx.x; i < n4; i += stride) {
    float4 v = *(const float4*)(xc + (size_t)i * 4);
    unsigned short o[4] = {f2bf(v.x), f2bf(v.y), f2bf(v.z), f2bf(v.w)};
    *(unsigned long long*)(xbf + (size_t)i * 4) = *(unsigned long long*)o;
  }
}

// ---------------- fused recurrence over one time-chunk [t0, t0+tc) ----------------
// 128 WGs x 256 threads (4 waves). WG owns 8 h-cols (32 gate cols, local n = g*8+jj).
// LDS: W_hh slice (masked) 64 KB + W_ih slice 64 KB, both [32][1024] bf16 XOR-swizzled.
// Per step: gx-part (x(t) @ W_ih^T) was accumulated into gxacc during the PREVIOUS
// iteration (fills the sync bubble; no sequential dependency). After the h(t-1) wait,
// the h-GEMM continues accumulating on top of gxacc. Sync/publish identical to R8:
// per-block flags -> block0 aggregates -> g_step; h via never-reused hring slots
// (LDS-gathered 16B UC stores, plain cached reads).
__global__ __launch_bounds__(256) void wdlstm_fused(
    const float* __restrict__ w_hh, const float* __restrict__ hh_mask,
    const float* __restrict__ w_ih,
    const float* __restrict__ b_ih, const float* __restrict__ b_hh,
    const unsigned short* __restrict__ xbf,  // [tc][B][I] bf16
    float* __restrict__ out, float* __restrict__ c_state,
    unsigned* __restrict__ flags,            // [NBLK] 64B-padded + g_step at +8192B
    unsigned short* __restrict__ hinit,      // [BH] cross-chunk h carry
    unsigned short* __restrict__ hring,      // [tc][BH] fresh slot per step
    int t0, int tc) {
  __shared__ __align__(16) char Wh[65536];       // [32][1024] bf16, XOR-swizzled
  __shared__ __align__(16) char Wi[65536];       // [32][1024] bf16, XOR-swizzled
  __shared__ float Dlds[64][35];                 // 64x32 D, pad 35
  __shared__ __align__(16) unsigned Hs[64][4];   // block's h-slice, packed bf16x2

  const int tid = threadIdx.x;
  const int wv  = tid >> 6, l = tid & 63;
  const int ln  = l & 15, lq = l >> 4;
  const int j0h = blockIdx.x * 8;
  unsigned* g_step = flags + 2048;               // +8192 B

  // preload W slices: LDS row n (0..31) = weight row (n>>3)*H + j0h + (n&7)
#pragma unroll
  for (int c8 = 0; c8 < 16; ++c8) {
    int c = tid + 256 * c8;          // 4096 chunks of 8 elems
    int n = c >> 7, cc = c & 127;
    int wrow = (n >> 3) * HH + j0h + (n & 7);
    int addr = (n * 2048 + cc * 16) ^ ((n & 7) << 4);
    {
      const float* sw = w_hh   + (size_t)wrow * HH + cc * 8;
      const float* sm = hh_mask + (size_t)wrow * HH + cc * 8;
      float4 w0 = *(const float4*)sw, w1 = *(const float4*)(sw + 4);
      float4 m0 = *(const float4*)sm, m1 = *(const float4*)(sm + 4);
      float4 p0 = {w0.x * m0.x, w0.y * m0.y, w0.z * m0.z, w0.w * m0.w};
      float4 p1 = {w1.x * m1.x, w1.y * m1.y, w1.z * m1.z, w1.w * m1.w};
      *(bf16x8*)(Wh + addr) = pack8(p0, p1);
    }
    {
      const float* si = w_ih + (size_t)wrow * II + cc * 8;
      float4 a0 = *(const float4*)si, a1 = *(const float4*)(si + 4);
      *(bf16x8*)(Wi + addr) = pack8(a0, a1);
    }
  }
  __syncthreads();

  // elementwise ownership: thread (wv, l) -> b = l, cols jj0 = 2*wv (+q, q=0..1)
  const int b_ep = l;
  const int jj0  = 2 * wv;
  float c_reg[2];
  if (t0 == 0) {
    c_reg[0] = c_reg[1] = 0.f;
  } else {
    float2 cv = *(const float2*)(c_state + (size_t)b_ep * HH + j0h + jj0);
    c_reg[0] = cv.x; c_reg[1] = cv.y;
  }
  float biasv[4][2];
#pragma unroll
  for (int g = 0; g < 4; ++g)
#pragma unroll
    for (int q = 0; q < 2; ++q) {
      int col = g * HH + j0h + jj0 + q;
      biasv[g][q] = b_ih[col] + b_hh[col];
    }

  float* hn_out = out + (size_t)TT * BH;
  float* cn_out = hn_out + BH;

  // input-GEMM for step lt into gxacc (A rows = b, from xbf; B = Wi slice)
  f32x4 gxacc[2];
  auto gx_compute = [&](int lt) {
    gxacc[0] = (f32x4){0.f, 0.f, 0.f, 0.f};
    gxacc[1] = (f32x4){0.f, 0.f, 0.f, 0.f};
    const unsigned short* ap = xbf + (size_t)lt * BH + (size_t)(16 * wv + ln) * II + lq * 8;
#pragma unroll 4
    for (int kc = 0; kc < 32; ++kc) {
      bf16x8 a = *(const bf16x8*)(ap + kc * 32);
#pragma unroll
      for (int ni = 0; ni < 2; ++ni) {
        int n = 16 * ni + ln;
        int baddr = (n * 2048 + kc * 64 + lq * 16) ^ ((n & 7) << 4);
        bf16x8 b = *(const bf16x8*)(Wi + baddr);
        gxacc[ni] = __builtin_amdgcn_mfma_f32_16x16x32_bf16(a, b, gxacc[ni], 0, 0, 0);
      }
    }
  };
  gx_compute(0);   // prologue: gx for the first step of this chunk

  for (int lt = 0; lt < tc; ++lt) {
    const int t = t0 + lt;

    f32x4 acc[2] = {gxacc[0], gxacc[1]};   // D starts from the input-GEMM part

    if (t > 0) {
      // ---- wait for h(t-1): hierarchical (identical to R8) ----
      if (blockIdx.x == 0) {
        if (tid < 64) {        // wave 0: poll two flags per lane
          const unsigned* f0 = flags + (2 * tid) * 16;
          const unsigned* f1 = flags + (2 * tid + 1) * 16;
          while ((int)ld32_uc(f0) < t || (int)ld32_uc(f1) < t)
            __builtin_amdgcn_s_sleep(1);
          if (tid == 0) st32_uc(g_step, (unsigned)t);
        }
        __syncthreads();
      } else {
        if (tid == 0) {
          while ((int)ld32_uc(g_step) < t) __builtin_amdgcn_s_sleep(1);
        }
        __syncthreads();
      }

      const unsigned short* hp = (lt == 0) ? hinit
                                           : hring + (size_t)(lt - 1) * BH;
      const unsigned short* ap = hp + (size_t)(16 * wv + ln) * HH + lq * 8;
#pragma unroll 4
      for (int kc = 0; kc < 32; ++kc) {
        bf16x8 a = *(const bf16x8*)(ap + kc * 32);   // cached, coalesced
#pragma unroll
        for (int ni = 0; ni < 2; ++ni) {
          int n = 16 * ni + ln;
          int baddr = (n * 2048 + kc * 64 + lq * 16) ^ ((n & 7) << 4);
          bf16x8 b = *(const bf16x8*)(Wh + baddr);
          acc[ni] = __builtin_amdgcn_mfma_f32_16x16x32_bf16(a, b, acc[ni], 0, 0, 0);
        }
      }
    }
    // transpose D through LDS: wave wv rows 16wv+4lq+r, cols 16ni+ln
#pragma unroll
    for (int ni = 0; ni < 2; ++ni)
#pragma unroll
      for (int r = 0; r < 4; ++r)
        Dlds[16 * wv + 4 * lq + r][16 * ni + ln] = acc[ni][r];
    __syncthreads();

    // ---- elementwise: 2 states per thread; D col n = g*8 + jj
    float hq[2];
#pragma unroll
    for (int q = 0; q < 2; ++q) {
      float g0 = Dlds[b_ep][ 0 + jj0 + q] + biasv[0][q];
      float g1 = Dlds[b_ep][ 8 + jj0 + q] + biasv[1][q];
      float g2 = Dlds[b_ep][16 + jj0 + q] + biasv[2][q];
      float g3 = Dlds[b_ep][24 + jj0 + q] + biasv[3][q];
      float ig = sigmoid_f(g0);
      float fg = sigmoid_f(g1);
      float gg = tanh_f(g2);
      float og = sigmoid_f(g3);
      c_reg[q] = fg * c_reg[q] + ig * gg;
      hq[q] = og * tanh_f(c_reg[q]);
    }
    *(float2*)(out + (size_t)t * BH + (size_t)b_ep * HH + j0h + jj0) = make_float2(hq[0], hq[1]);
    Hs[b_ep][wv] = (unsigned)f2bf(hq[0]) | ((unsigned)f2bf(hq[1]) << 16);
    if (t == TT - 1) {
      *(float2*)(hn_out + (size_t)b_ep * HH + j0h + jj0) = make_float2(hq[0], hq[1]);
      *(float2*)(cn_out + (size_t)b_ep * HH + j0h + jj0) = make_float2(c_reg[0], c_reg[1]);
    }

    __syncthreads();   // Hs complete; Dlds consumed

    // ---- publish: wave 0 stores the block's 64x8 h-slice as 64 x 16B UC lines
    if (wv == 0) {
      u32x4 hv4 = *(const u32x4*)&Hs[l][0];
      char* dst = (char*)hring + ((size_t)lt * BH + (size_t)l * HH + j0h) * 2;
      st128_uc(dst, hv4);
      if (lt == tc - 1) {   // cross-chunk carry
        char* dsti = (char*)hinit + ((size_t)l * HH + j0h) * 2;
        st128_uc(dsti, hv4);
      }
      asm volatile("s_waitcnt vmcnt(0)" ::: "memory");
      if (tid == 0) st32_uc(&flags[blockIdx.x * 16], (unsigned)(t + 1));
    }

    // ---- input-GEMM for the NEXT step: fills other blocks' sync bubble
    if (lt + 1 < tc) gx_compute(lt + 1);
  }

  // persist c across chunk launches
  *(float2*)(c_state + (size_t)b_ep * HH + j0h + jj0) = make_float2(c_reg[0], c_reg[1]);
}

extern "C" void kernel_launch(void* const* d_in, const int* in_sizes, int n_in,
                              void* d_out, int out_size, void* d_ws, size_t ws_size,
                              hipStream_t stream) {
  const float* x       = (const float*)d_in[0];
  const float* w_ih    = (const float*)d_in[1];
  const float* w_hh    = (const float*)d_in[2];
  const float* b_ih    = (const float*)d_in[3];
  const float* b_hh    = (const float*)d_in[4];
  const float* hh_mask = (const float*)d_in[5];
  float* out           = (float*)d_out;

  char* ws = (char*)d_ws;
  float* c_state        = (float*)ws;                           // 262144 B
  unsigned* flags       = (unsigned*)(ws + 262144);             // 16384 B (128x64B + g_step)
  unsigned short* hinit = (unsigned short*)(ws + 278528);       // 131072 B
  unsigned short* hring = (unsigned short*)(ws + 409600);       // TC x 131072 B
  // xbf placed after hring (TC-dependent)

  // adaptive time-chunk: per step needs 128KB (hring) + 128KB (xbf)
  const long long fixed = 409600;
  const long long per_t = 131072 + 131072;
  long long avail = (long long)ws_size - fixed;
  int TC = (int)(avail / per_t);
  if (TC > 128) TC = 128;
  if (TC < 2) TC = 2;
  unsigned short* xbf = (unsigned short*)(ws + 409600 + (size_t)TC * 131072);

  // reset flags + g_step once per launch (graph-capture-safe async memset)
  hipMemsetAsync(flags, 0, 16384, stream);

  for (int t0 = 0; t0 < TT; t0 += TC) {
    int tc = TT - t0 < TC ? TT - t0 : TC;
    const float* xc = x + (size_t)t0 * BB * II;
    wdlstm_xconv<<<256, 256, 0, stream>>>(xc, xbf, tc * BH / 4);
    wdlstm_fused<<<NBLK, 256, 0, stream>>>(w_hh, hh_mask, w_ih, b_ih, b_hh, xbf,
                                           out, c_state, flags, hinit, hring, t0, tc);
  }
}

// Round 10
// 4584.637 us; speedup vs baseline: 1.0172x; 1.0172x over previous
//
#include <hip/hip_runtime.h>

#define TT 512
#define BB 64
#define II 1024
#define HH 1024
#define GG 4096   /* 4*H */
#define BH 65536  /* B*H */
#define NBLK 128

typedef __attribute__((ext_vector_type(8))) short bf16x8;
typedef __attribute__((ext_vector_type(4))) float f32x4;
typedef __attribute__((ext_vector_type(4))) unsigned u32x4;

__device__ __forceinline__ float bf2f(unsigned short u) {
  union { unsigned int i; float f; } v; v.i = ((unsigned int)u) << 16; return v.f;
}
__device__ __forceinline__ unsigned short f2bf(float f) {
  union { float f; unsigned int i; } v; v.f = f;
  return (unsigned short)((v.i + 0x7FFFu + ((v.i >> 16) & 1u)) >> 16);
}
__device__ __forceinline__ bf16x8 pack8(float4 a, float4 b) {
  union { bf16x8 v; unsigned short u[8]; } p;
  p.u[0] = f2bf(a.x); p.u[1] = f2bf(a.y); p.u[2] = f2bf(a.z); p.u[3] = f2bf(a.w);
  p.u[4] = f2bf(b.x); p.u[5] = f2bf(b.y); p.u[6] = f2bf(b.z); p.u[7] = f2bf(b.w);
  return p.v;
}
__device__ __forceinline__ float sigmoid_f(float x) { return 1.0f / (1.0f + __expf(-x)); }
__device__ __forceinline__ float tanh_f(float x) {
  float e = __expf(-2.0f * fabsf(x));
  float t = (1.0f - e) / (1.0f + e);
  return copysignf(t, x);
}

__device__ __forceinline__ void st32_uc(unsigned* p, unsigned v) {
  __hip_atomic_store(p, v, __ATOMIC_RELAXED, __HIP_MEMORY_SCOPE_AGENT);
}
__device__ __forceinline__ unsigned ld32_uc(const unsigned* p) {
  return __hip_atomic_load(p, __ATOMIC_RELAXED, __HIP_MEMORY_SCOPE_AGENT);
}
// 16B write-through to the coherence point (non-atomic; aligned 16B = 1 transaction)
__device__ __forceinline__ void st128_uc(void* p, u32x4 v) {
  asm volatile("global_store_dwordx4 %0, %1, off sc0 sc1" :: "v"(p), "v"(v) : "memory");
}

// ---------------- x f32 -> bf16 chunk conversion ----------------
__global__ __launch_bounds__(256) void wdlstm_xconv(
    const float* __restrict__ xc, unsigned short* __restrict__ xbf, int n4) {
  int stride = gridDim.x * blockDim.x;
  for (int i = blockIdx.x * blockDim.x + threadIdx.x; i < n4; i += stride) {
    float4 v = *(const float4*)(xc + (size_t)i * 4);
    unsigned short o[4] = {f2bf(v.x), f2bf(v.y), f2bf(v.z), f2bf(v.w)};
    *(unsigned long long*)(xbf + (size_t)i * 4) = *(unsigned long long*)o;
  }
}

// ---------------- fused recurrence over one time-chunk [t0, t0+tc) ----------------
// 128 WGs x 512 threads (8 waves, 2/SIMD). WG owns 8 h-cols (32 gate cols n=g*8+jj).
// Wave w: A-rows 16*(w&3).., K-half (w>>2) of 1024 -> 16 reg-staged loads + 32 MFMA
// per GEMM; partials summed via Dlds[2]. gx-part for step t+1 computed after
// publishing h(t) (fills the sync bubble). Sync/publish identical to R8/R9.
__global__ __launch_bounds__(512) void wdlstm_fused(
    const float* __restrict__ w_hh, const float* __restrict__ hh_mask,
    const float* __restrict__ w_ih,
    const float* __restrict__ b_ih, const float* __restrict__ b_hh,
    const unsigned short* __restrict__ xbf,  // [tc][B][I] bf16
    float* __restrict__ out, float* __restrict__ c_state,
    unsigned* __restrict__ flags,            // [NBLK] 64B-padded + g_step at +8192B
    unsigned short* __restrict__ hinit,      // [BH] cross-chunk h carry
    unsigned short* __restrict__ hring,      // [tc][BH] fresh slot per step
    int t0, int tc) {
  __shared__ __align__(16) char Wh[65536];         // [32][1024] bf16, XOR-swizzled
  __shared__ __align__(16) char Wi[65536];         // [32][1024] bf16, XOR-swizzled
  __shared__ float Dlds[2][64][35];                // split-K partials, pad 35
  __shared__ __align__(16) unsigned short Hs[64][8];

  const int tid = threadIdx.x;
  const int wv  = tid >> 6, l = tid & 63;
  const int ln  = l & 15, lq = l >> 4;
  const int r0  = 16 * (wv & 3);     // A row group
  const int kh  = wv >> 2;           // K half (0/1)
  const int j0h = blockIdx.x * 8;
  unsigned* g_step = flags + 2048;   // +8192 B

  // preload W slices: LDS row n (0..31) = weight row (n>>3)*H + j0h + (n&7)
#pragma unroll
  for (int c8 = 0; c8 < 8; ++c8) {
    int c = tid + 512 * c8;          // 4096 chunks of 8 elems
    int n = c >> 7, cc = c & 127;
    int wrow = (n >> 3) * HH + j0h + (n & 7);
    int addr = (n * 2048 + cc * 16) ^ ((n & 7) << 4);
    {
      const float* sw = w_hh   + (size_t)wrow * HH + cc * 8;
      const float* sm = hh_mask + (size_t)wrow * HH + cc * 8;
      float4 w0 = *(const float4*)sw, w1 = *(const float4*)(sw + 4);
      float4 m0 = *(const float4*)sm, m1 = *(const float4*)(sm + 4);
      float4 p0 = {w0.x * m0.x, w0.y * m0.y, w0.z * m0.z, w0.w * m0.w};
      float4 p1 = {w1.x * m1.x, w1.y * m1.y, w1.z * m1.z, w1.w * m1.w};
      *(bf16x8*)(Wh + addr) = pack8(p0, p1);
    }
    {
      const float* si = w_ih + (size_t)wrow * II + cc * 8;
      float4 a0 = *(const float4*)si, a1 = *(const float4*)(si + 4);
      *(bf16x8*)(Wi + addr) = pack8(a0, a1);
    }
  }
  __syncthreads();

  // elementwise ownership: thread -> (b = tid&63, col jc = tid>>6, 0..7)
  const int b_ep = tid & 63;
  const int jc   = tid >> 6;
  float c_reg;
  if (t0 == 0) c_reg = 0.f;
  else         c_reg = c_state[(size_t)b_ep * HH + j0h + jc];
  float biasv[4];
#pragma unroll
  for (int g = 0; g < 4; ++g) {
    int col = g * HH + j0h + jc;
    biasv[g] = b_ih[col] + b_hh[col];
  }

  float* hn_out = out + (size_t)TT * BH;
  float* cn_out = hn_out + BH;

  // input-GEMM partial for step lt (this wave's K-half), reg-staged 16-deep
  f32x4 gxacc[2];
  auto gx_compute = [&](int lt) {
    gxacc[0] = (f32x4){0.f, 0.f, 0.f, 0.f};
    gxacc[1] = (f32x4){0.f, 0.f, 0.f, 0.f};
    const unsigned short* ap = xbf + (size_t)lt * BH + (size_t)(r0 + ln) * II + kh * 512 + lq * 8;
    bf16x8 areg[16];
#pragma unroll
    for (int i = 0; i < 16; ++i) areg[i] = *(const bf16x8*)(ap + i * 32);
#pragma unroll
    for (int i = 0; i < 16; ++i) {
      int kb = kh * 1024 + i * 64;      // byte offset of k-base within a W row
#pragma unroll
      for (int ni = 0; ni < 2; ++ni) {
        int n = 16 * ni + ln;
        int baddr = (n * 2048 + kb + lq * 16) ^ ((n & 7) << 4);
        bf16x8 b = *(const bf16x8*)(Wi + baddr);
        gxacc[ni] = __builtin_amdgcn_mfma_f32_16x16x32_bf16(areg[i], b, gxacc[ni], 0, 0, 0);
      }
    }
  };
  gx_compute(0);   // prologue: gx for the first step of this chunk

  for (int lt = 0; lt < tc; ++lt) {
    const int t = t0 + lt;

    f32x4 acc[2] = {gxacc[0], gxacc[1]};   // D starts from the input-GEMM partial

    if (t > 0) {
      // ---- wait for h(t-1): hierarchical (identical to R8/R9) ----
      if (blockIdx.x == 0) {
        if (tid < 64) {        // wave 0: poll two flags per lane
          const unsigned* f0 = flags + (2 * tid) * 16;
          const unsigned* f1 = flags + (2 * tid + 1) * 16;
          while ((int)ld32_uc(f0) < t || (int)ld32_uc(f1) < t)
            __builtin_amdgcn_s_sleep(1);
          if (tid == 0) st32_uc(g_step, (unsigned)t);
        }
        __syncthreads();
      } else {
        if (tid == 0) {
          while ((int)ld32_uc(g_step) < t) __builtin_amdgcn_s_sleep(1);
        }
        __syncthreads();
      }

      const unsigned short* hp = (lt == 0) ? hinit
                                           : hring + (size_t)(lt - 1) * BH;
      const unsigned short* ap = hp + (size_t)(r0 + ln) * HH + kh * 512 + lq * 8;
      bf16x8 areg[16];
#pragma unroll
      for (int i = 0; i < 16; ++i) areg[i] = *(const bf16x8*)(ap + i * 32);
#pragma unroll
      for (int i = 0; i < 16; ++i) {
        int kb = kh * 1024 + i * 64;
#pragma unroll
        for (int ni = 0; ni < 2; ++ni) {
          int n = 16 * ni + ln;
          int baddr = (n * 2048 + kb + lq * 16) ^ ((n & 7) << 4);
          bf16x8 b = *(const bf16x8*)(Wh + baddr);
          acc[ni] = __builtin_amdgcn_mfma_f32_16x16x32_bf16(areg[i], b, acc[ni], 0, 0, 0);
        }
      }
    }
    // write split-K partial: wave (r0, kh) -> Dlds[kh][r0+4lq+r][16ni+ln]
#pragma unroll
    for (int ni = 0; ni < 2; ++ni)
#pragma unroll
      for (int r = 0; r < 4; ++r)
        Dlds[kh][r0 + 4 * lq + r][16 * ni + ln] = acc[ni][r];
    __syncthreads();

    // ---- elementwise: 1 state per thread; gate col n = g*8 + jc
    float g0 = Dlds[0][b_ep][ 0 + jc] + Dlds[1][b_ep][ 0 + jc] + biasv[0];
    float g1 = Dlds[0][b_ep][ 8 + jc] + Dlds[1][b_ep][ 8 + jc] + biasv[1];
    float g2 = Dlds[0][b_ep][16 + jc] + Dlds[1][b_ep][16 + jc] + biasv[2];
    float g3 = Dlds[0][b_ep][24 + jc] + Dlds[1][b_ep][24 + jc] + biasv[3];
    float ig = sigmoid_f(g0);
    float fg = sigmoid_f(g1);
    float gg = tanh_f(g2);
    float og = sigmoid_f(g3);
    c_reg = fg * c_reg + ig * gg;
    float h = og * tanh_f(c_reg);
    out[(size_t)t * BH + (size_t)b_ep * HH + j0h + jc] = h;
    Hs[b_ep][jc] = f2bf(h);
    if (t == TT - 1) {
      hn_out[(size_t)b_ep * HH + j0h + jc] = h;
      cn_out[(size_t)b_ep * HH + j0h + jc] = c_reg;
    }

    __syncthreads();   // Hs complete; Dlds consumed

    // ---- publish: wave 0 stores the block's 64x8 h-slice as 64 x 16B UC lines
    if (wv == 0) {
      u32x4 hv4 = *(const u32x4*)&Hs[l][0];
      char* dst = (char*)hring + ((size_t)lt * BH + (size_t)l * HH + j0h) * 2;
      st128_uc(dst, hv4);
      if (lt == tc - 1) {   // cross-chunk carry
        char* dsti = (char*)hinit + ((size_t)l * HH + j0h) * 2;
        st128_uc(dsti, hv4);
      }
      asm volatile("s_waitcnt vmcnt(0)" ::: "memory");
      if (tid == 0) st32_uc(&flags[blockIdx.x * 16], (unsigned)(t + 1));
    }

    // ---- input-GEMM partial for the NEXT step: fills the sync bubble
    if (lt + 1 < tc) gx_compute(lt + 1);
  }

  // persist c across chunk launches
  c_state[(size_t)b_ep * HH + j0h + jc] = c_reg;
}

extern "C" void kernel_launch(void* const* d_in, const int* in_sizes, int n_in,
                              void* d_out, int out_size, void* d_ws, size_t ws_size,
                              hipStream_t stream) {
  const float* x       = (const float*)d_in[0];
  const float* w_ih    = (const float*)d_in[1];
  const float* w_hh    = (const float*)d_in[2];
  const float* b_ih    = (const float*)d_in[3];
  const float* b_hh    = (const float*)d_in[4];
  const float* hh_mask = (const float*)d_in[5];
  float* out           = (float*)d_out;

  char* ws = (char*)d_ws;
  float* c_state        = (float*)ws;                           // 262144 B
  unsigned* flags       = (unsigned*)(ws + 262144);             // 16384 B (128x64B + g_step)
  unsigned short* hinit = (unsigned short*)(ws + 278528);       // 131072 B
  unsigned short* hring = (unsigned short*)(ws + 409600);       // TC x 131072 B
  // xbf placed after hring (TC-dependent)

  // adaptive time-chunk: per step needs 128KB (hring) + 128KB (xbf)
  const long long fixed = 409600;
  const long long per_t = 131072 + 131072;
  long long avail = (long long)ws_size - fixed;
  int TC = (int)(avail / per_t);
  if (TC > 128) TC = 128;
  if (TC < 2) TC = 2;
  unsigned short* xbf = (unsigned short*)(ws + 409600 + (size_t)TC * 131072);

  // reset flags + g_step once per launch (graph-capture-safe async memset)
  hipMemsetAsync(flags, 0, 16384, stream);

  for (int t0 = 0; t0 < TT; t0 += TC) {
    int tc = TT - t0 < TC ? TT - t0 : TC;
    const float* xc = x + (size_t)t0 * BB * II;
    wdlstm_xconv<<<256, 256, 0, stream>>>(xc, xbf, tc * BH / 4);
    wdlstm_fused<<<NBLK, 512, 0, stream>>>(w_hh, hh_mask, w_ih, b_ih, b_hh, xbf,
                                           out, c_state, flags, hinit, hring, t0, tc);
  }
}